// Round 3
// baseline (624.462 us; speedup 1.0000x reference)
//
#include <hip/hip_runtime.h>
#include <math.h>

#define NN 50000
#define EE 800000
#define FIN 128
#define FOUT 32
#define HEADS 8
#define NT 16
#define HF 256          // HEADS*FOUT
#define TH (NT*HEADS)   // 128

// ---- Kernel A: projection + a1 + node_type, NPB nodes per 256-thread block ----
#define NPB 8
__global__ __launch_bounds__(256) void k_project(
    const float* __restrict__ x, const float* __restrict__ fc_w,
    const float* __restrict__ attn_l, const float* __restrict__ attn_r,
    float* __restrict__ nf, float* __restrict__ a1, float* __restrict__ nt)
{
    __shared__ float xs[NPB][FIN];
    __shared__ float ps[NPB][HF];
    const int t = threadIdx.x;
    const int node0 = blockIdx.x * NPB;

    for (int i = t; i < NPB * FIN; i += 256) {
        int ni = i >> 7, k = i & 127;
        int n = node0 + ni;
        xs[ni][k] = (n < NN) ? x[n * FIN + k] : 0.f;
    }
    __syncthreads();

    float acc[NPB];
#pragma unroll
    for (int i = 0; i < NPB; i++) acc[i] = 0.f;
    for (int k = 0; k < FIN; k++) {
        float w = fc_w[k * HF + t];
#pragma unroll
        for (int i = 0; i < NPB; i++) acc[i] += xs[i][k] * w;
    }
#pragma unroll
    for (int i = 0; i < NPB; i++) {
        ps[i][t] = acc[i];
        int n = node0 + i;
        if (n < NN) nf[n * HF + t] = acc[i];
    }
    __syncthreads();

    if (t < NPB * HEADS) {
        int ni = t >> 3, h = t & 7;
        float s = 0.f;
#pragma unroll
        for (int f = 0; f < FOUT; f++) s += ps[ni][f * HEADS + h] * attn_l[f * HEADS + h];
        int n = node0 + ni;
        if (n < NN) a1[n * HEADS + h] = s;
    }
    for (int task = t; task < NPB * TH; task += 256) {
        int ni = task / TH;
        int rem = task % TH;
        int tt = rem >> 3, h = rem & 7;
        const float* ar = attn_r + tt * (FOUT * HEADS);
        float s = 0.f;
#pragma unroll
        for (int f = 0; f < FOUT; f++) s += ps[ni][f * HEADS + h] * ar[f * HEADS + h];
        int n = node0 + ni;
        if (n < NN) nt[n * TH + rem] = s;
    }
}

// ---- CSR build: histogram of dst ----
__global__ __launch_bounds__(256) void k_hist(
    const int* __restrict__ dst, int* __restrict__ deg)
{
    int e = blockIdx.x * 256 + threadIdx.x;
    if (e >= EE) return;
    atomicAdd(&deg[dst[e]], 1);
}

// ---- CSR build: single-block exclusive scan over deg -> rowptr ----
#define SCAN_T 1024
__global__ __launch_bounds__(1024) void k_scan(
    const int* __restrict__ deg, int* __restrict__ rowptr)
{
    __shared__ int part[SCAN_T];
    const int t = threadIdx.x;
    const int CH = (NN + SCAN_T - 1) / SCAN_T;  // 49
    int begin = t * CH;
    int end = begin + CH; if (end > NN) end = NN;
    if (begin > NN) begin = NN;
    int s = 0;
    for (int i = begin; i < end; i++) s += deg[i];
    part[t] = s;
    __syncthreads();
    for (int off = 1; off < SCAN_T; off <<= 1) {
        int v = (t >= off) ? part[t - off] : 0;
        __syncthreads();
        part[t] += v;
        __syncthreads();
    }
    int excl = (t == 0) ? 0 : part[t - 1];
    for (int i = begin; i < end; i++) {
        rowptr[i] = excl;
        excl += deg[i];
    }
}

// ---- CSR build: scatter edge ids ----
__global__ __launch_bounds__(256) void k_scatter(
    const int* __restrict__ dst, const int* __restrict__ rowptr,
    int* __restrict__ cursor, int* __restrict__ eidx)
{
    int e = blockIdx.x * 256 + threadIdx.x;
    if (e >= EE) return;
    int d = dst[e];
    int pos = atomicAdd(&cursor[d], 1);
    eidx[rowptr[d] + pos] = e;
}

// ---- Fully fused per-node kernel: logits + softmax + aggregate + epilogue ----
// One 64-lane wave per dst node; lane owns columns j = lane*4 .. lane*4+3,
// whose heads are h = half*4+c with half = lane&1.
__global__ __launch_bounds__(256) void k_fused(
    const float* __restrict__ nf, const float* __restrict__ a1,
    const float* __restrict__ nt,
    const int* __restrict__ src, const int* __restrict__ et,
    const int* __restrict__ rowptr, const int* __restrict__ deg,
    const int* __restrict__ eidx, const float* __restrict__ bias,
    float* __restrict__ A, float* __restrict__ ret)
{
    const int wave = threadIdx.x >> 6;
    const int lane = threadIdx.x & 63;
    const int n = blockIdx.x * 4 + wave;
    if (n >= NN) return;
    const int start = rowptr[n];
    const int cnt = deg[n];
    const int half = lane & 1;

    const float4 a1v = *(const float4*)(&a1[n * HEADS + half * 4]);

    // ---- Pass 1: logits + per-head running max (every lane sees every edge) ----
    float4 m4 = make_float4(-1e30f, -1e30f, -1e30f, -1e30f);
    for (int i = 0; i < cnt; i++) {
        int e = eidx[start + i];
        int s = src[e], ty = et[e];
        float4 r = *(const float4*)(&nt[s * TH + ty * HEADS + half * 4]);
        float4 a;
        a.x = a1v.x + r.x; a.y = a1v.y + r.y;
        a.z = a1v.z + r.z; a.w = a1v.w + r.w;
        a.x = (a.x > 0.f) ? a.x : 0.2f * a.x;
        a.y = (a.y > 0.f) ? a.y : 0.2f * a.y;
        a.z = (a.z > 0.f) ? a.z : 0.2f * a.z;
        a.w = (a.w > 0.f) ? a.w : 0.2f * a.w;
        m4.x = fmaxf(m4.x, a.x); m4.y = fmaxf(m4.y, a.y);
        m4.z = fmaxf(m4.z, a.z); m4.w = fmaxf(m4.w, a.w);
        if (lane < 2) *(float4*)(&A[e * HEADS + lane * 4]) = a;  // logits scratch
    }

    // ---- Pass 2: ex = exp(a-m); den += ex; acc += ex * nf[src] ----
    float4 den = make_float4(0.f, 0.f, 0.f, 0.f);
    float4 acc = make_float4(0.f, 0.f, 0.f, 0.f);
    for (int i = 0; i < cnt; i++) {
        int e = eidx[start + i];
        int s = src[e];
        float4 a = *(const float4*)(&A[e * HEADS + half * 4]);
        float4 ex;
        ex.x = expf(a.x - m4.x); ex.y = expf(a.y - m4.y);
        ex.z = expf(a.z - m4.z); ex.w = expf(a.w - m4.w);
        den.x += ex.x; den.y += ex.y; den.z += ex.z; den.w += ex.w;
        float4 v = *(const float4*)(&nf[(size_t)s * HF + lane * 4]);
        acc.x += v.x * ex.x; acc.y += v.y * ex.y;
        acc.z += v.z * ex.z; acc.w += v.w * ex.w;
    }
    float4 inv;
    inv.x = (den.x > 0.f) ? 1.f / den.x : 0.f;
    inv.y = (den.y > 0.f) ? 1.f / den.y : 0.f;
    inv.z = (den.z > 0.f) ? 1.f / den.z : 0.f;
    inv.w = (den.w > 0.f) ? 1.f / den.w : 0.f;

    // ---- Pass 3: final attn write (lane c<2 handles half==c with its own m/inv) ----
    for (int i = 0; i < cnt; i++) {
        int e = eidx[start + i];
        if (lane < 2) {
            float4 a = *(const float4*)(&A[e * HEADS + lane * 4]);
            float4 at;
            at.x = expf(a.x - m4.x) * inv.x;
            at.y = expf(a.y - m4.y) * inv.y;
            at.z = expf(a.z - m4.z) * inv.z;
            at.w = expf(a.w - m4.w) * inv.w;
            *(float4*)(&A[e * HEADS + lane * 4]) = at;
        }
    }

    // ---- Epilogue: normalize acc, + bias, head-mean via coset reduce, ELU ----
    acc.x *= inv.x; acc.y *= inv.y; acc.z *= inv.z; acc.w *= inv.w;
    float4 b = *(const float4*)(&bias[lane * 4]);
    acc.x += b.x; acc.y += b.y; acc.z += b.z; acc.w += b.w;

    for (int m = 8; m <= 32; m <<= 1) {
        acc.x += __shfl_xor(acc.x, m, 64);
        acc.y += __shfl_xor(acc.y, m, 64);
        acc.z += __shfl_xor(acc.z, m, 64);
        acc.w += __shfl_xor(acc.w, m, 64);
    }
    if (lane < 8) {
        float4 o;
        o.x = acc.x * 0.125f; o.y = acc.y * 0.125f;
        o.z = acc.z * 0.125f; o.w = acc.w * 0.125f;
        o.x = (o.x > 0.f) ? o.x : (expf(o.x) - 1.f);
        o.y = (o.y > 0.f) ? o.y : (expf(o.y) - 1.f);
        o.z = (o.z > 0.f) ? o.z : (expf(o.z) - 1.f);
        o.w = (o.w > 0.f) ? o.w : (expf(o.w) - 1.f);
        *(float4*)(&ret[n * FOUT + lane * 4]) = o;
    }
}

extern "C" void kernel_launch(void* const* d_in, const int* in_sizes, int n_in,
                              void* d_out, int out_size, void* d_ws, size_t ws_size,
                              hipStream_t stream)
{
    const float* x      = (const float*)d_in[0];
    const float* fc_w   = (const float*)d_in[1];
    const float* attn_l = (const float*)d_in[2];
    const float* attn_r = (const float*)d_in[3];
    const float* bias   = (const float*)d_in[4];
    const int*   src    = (const int*)d_in[5];
    const int*   dst    = (const int*)d_in[6];
    const int*   etype  = (const int*)d_in[7];

    float* out_attn = (float*)d_out;                 // [E, 1, HEADS]
    float* out_ret  = out_attn + (size_t)EE * HEADS; // [N, FOUT]

    // workspace layout (bytes)
    char* ws = (char*)d_ws;
    float* nf     = (float*)(ws);                    // 51.2 MB
    float* a1     = (float*)(ws + 51200000);         // 1.6 MB
    float* nt     = (float*)(ws + 56000000);         // 25.6 MB
    int*   deg    = (int*)(ws + 81600000);           // 200 KB
    int*   cursor = (int*)(ws + 81800000);           // 200 KB
    int*   rowptr = (int*)(ws + 82000000);           // 200 KB
    int*   eidx   = (int*)(ws + 82200192);           // 3.2 MB

    hipMemsetAsync(deg, 0, (size_t)400000, stream);  // deg + cursor (contiguous)

    k_project<<<(NN + NPB - 1) / NPB, 256, 0, stream>>>(x, fc_w, attn_l, attn_r, nf, a1, nt);

    k_hist<<<(EE + 255) / 256, 256, 0, stream>>>(dst, deg);
    k_scan<<<1, SCAN_T, 0, stream>>>(deg, rowptr);
    k_scatter<<<(EE + 255) / 256, 256, 0, stream>>>(dst, rowptr, cursor, eidx);

    k_fused<<<(NN + 3) / 4, 256, 0, stream>>>(nf, a1, nt, src, etype,
                                              rowptr, deg, eidx, bias,
                                              out_attn, out_ret);
}

// Round 4
// 475.440 us; speedup vs baseline: 1.3134x; 1.3134x over previous
//
#include <hip/hip_runtime.h>
#include <hip/hip_bf16.h>
#include <math.h>

#define NN 50000
#define EE 800000
#define FIN 128
#define FOUT 32
#define HEADS 8
#define NT 16
#define HF 256          // HEADS*FOUT
#define TH (NT*HEADS)   // 128

// ---- Kernel A: projection + a1 + node_type; nf stored as bf16 ----
#define NPB 8
__global__ __launch_bounds__(256) void k_project(
    const float* __restrict__ x, const float* __restrict__ fc_w,
    const float* __restrict__ attn_l, const float* __restrict__ attn_r,
    __hip_bfloat16* __restrict__ nfh, float* __restrict__ a1,
    float* __restrict__ nt)
{
    __shared__ float xs[NPB][FIN];
    __shared__ float ps[NPB][HF];
    const int t = threadIdx.x;
    const int node0 = blockIdx.x * NPB;

    for (int i = t; i < NPB * FIN; i += 256) {
        int ni = i >> 7, k = i & 127;
        int n = node0 + ni;
        xs[ni][k] = (n < NN) ? x[n * FIN + k] : 0.f;
    }
    __syncthreads();

    float acc[NPB];
#pragma unroll
    for (int i = 0; i < NPB; i++) acc[i] = 0.f;
    for (int k = 0; k < FIN; k++) {
        float w = fc_w[k * HF + t];
#pragma unroll
        for (int i = 0; i < NPB; i++) acc[i] += xs[i][k] * w;
    }
#pragma unroll
    for (int i = 0; i < NPB; i++) {
        ps[i][t] = acc[i];
        int n = node0 + i;
        if (n < NN) nfh[(size_t)n * HF + t] = __float2bfloat16(acc[i]);
    }
    __syncthreads();

    if (t < NPB * HEADS) {
        int ni = t >> 3, h = t & 7;
        float s = 0.f;
#pragma unroll
        for (int f = 0; f < FOUT; f++) s += ps[ni][f * HEADS + h] * attn_l[f * HEADS + h];
        int n = node0 + ni;
        if (n < NN) a1[n * HEADS + h] = s;
    }
    for (int task = t; task < NPB * TH; task += 256) {
        int ni = task / TH;
        int rem = task % TH;
        int tt = rem >> 3, h = rem & 7;
        const float* ar = attn_r + tt * (FOUT * HEADS);
        float s = 0.f;
#pragma unroll
        for (int f = 0; f < FOUT; f++) s += ps[ni][f * HEADS + h] * ar[f * HEADS + h];
        int n = node0 + ni;
        if (n < NN) nt[n * TH + rem] = s;
    }
}

// ---- CSR build: histogram of dst ----
__global__ __launch_bounds__(256) void k_hist(
    const int* __restrict__ dst, int* __restrict__ deg)
{
    int e = blockIdx.x * 256 + threadIdx.x;
    if (e >= EE) return;
    atomicAdd(&deg[dst[e]], 1);
}

// ---- CSR build: single-block exclusive scan over deg -> rowptr ----
#define SCAN_T 1024
__global__ __launch_bounds__(1024) void k_scan(
    const int* __restrict__ deg, int* __restrict__ rowptr)
{
    __shared__ int part[SCAN_T];
    const int t = threadIdx.x;
    const int CH = (NN + SCAN_T - 1) / SCAN_T;  // 49
    int begin = t * CH;
    int end = begin + CH; if (end > NN) end = NN;
    if (begin > NN) begin = NN;
    int s = 0;
    for (int i = begin; i < end; i++) s += deg[i];
    part[t] = s;
    __syncthreads();
    for (int off = 1; off < SCAN_T; off <<= 1) {
        int v = (t >= off) ? part[t - off] : 0;
        __syncthreads();
        part[t] += v;
        __syncthreads();
    }
    int excl = (t == 0) ? 0 : part[t - 1];
    for (int i = begin; i < end; i++) {
        rowptr[i] = excl;
        excl += deg[i];
    }
}

// ---- CSR build: scatter edge ids ----
__global__ __launch_bounds__(256) void k_scatter(
    const int* __restrict__ dst, const int* __restrict__ rowptr,
    int* __restrict__ cursor, int* __restrict__ eidx)
{
    int e = blockIdx.x * 256 + threadIdx.x;
    if (e >= EE) return;
    int d = dst[e];
    int pos = atomicAdd(&cursor[d], 1);
    eidx[rowptr[d] + pos] = e;
}

// ---- Kernel B: edge logit + leaky relu + exp (no max: logits are O(1)) + den ----
__global__ __launch_bounds__(256) void k_edge(
    const float* __restrict__ a1, const float* __restrict__ nt,
    const int* __restrict__ src, const int* __restrict__ dst,
    const int* __restrict__ et,
    float* __restrict__ A, float* __restrict__ den)
{
    int idx = blockIdx.x * 256 + threadIdx.x;
    if (idx >= EE * HEADS) return;
    int e = idx >> 3, h = idx & 7;
    int d = dst[e], s = src[e], ty = et[e];
    float a = a1[d * HEADS + h] + nt[s * TH + ty * HEADS + h];
    a = (a > 0.f) ? a : 0.2f * a;
    float ex = expf(a);
    A[idx] = ex;
    atomicAdd(&den[d * HEADS + h], ex);
}

// ---- Fused: attn normalize (write-back) + gather-aggregate + bias/mean/ELU ----
// One 64-lane wave per dst node; lane owns columns j = lane*4 .. lane*4+3.
__global__ __launch_bounds__(256) void k_aggfused(
    const __hip_bfloat16* __restrict__ nfh, const int* __restrict__ src,
    const int* __restrict__ rowptr, const int* __restrict__ deg,
    const int* __restrict__ eidx, const float* __restrict__ den,
    const float* __restrict__ bias, float* __restrict__ A,
    float* __restrict__ ret)
{
    const int wave = threadIdx.x >> 6;
    const int lane = threadIdx.x & 63;
    const int n = blockIdx.x * 4 + wave;
    if (n >= NN) return;
    const int start = rowptr[n];
    const int cnt = deg[n];
    const int half = lane & 1;  // heads of columns lane*4+c are half*4+c

    float4 invden;
    {
        float4 dn = *(const float4*)(&den[n * HEADS + half * 4]);
        invden.x = (dn.x > 0.f) ? 1.f / dn.x : 0.f;
        invden.y = (dn.y > 0.f) ? 1.f / dn.y : 0.f;
        invden.z = (dn.z > 0.f) ? 1.f / dn.z : 0.f;
        invden.w = (dn.w > 0.f) ? 1.f / dn.w : 0.f;
    }
    float4 acc = make_float4(0.f, 0.f, 0.f, 0.f);

    for (int i = 0; i < cnt; i++) {
        int e = eidx[start + i];
        int s = src[e];
        float4 ex = *(const float4*)(&A[e * HEADS + half * 4]);
        float4 at = make_float4(ex.x * invden.x, ex.y * invden.y,
                                ex.z * invden.z, ex.w * invden.w);
        if (lane < 2) *(float4*)(&A[e * HEADS + lane * 4]) = at;  // final attn
        // bf16 message row: 4 elems = 8 bytes per lane
        const ushort* vh = (const ushort*)(&nfh[(size_t)s * HF + lane * 4]);
        ushort4 u = *(const ushort4*)vh;
        float4 v;
        v.x = __bfloat162float(*(const __hip_bfloat16*)&u.x);
        v.y = __bfloat162float(*(const __hip_bfloat16*)&u.y);
        v.z = __bfloat162float(*(const __hip_bfloat16*)&u.z);
        v.w = __bfloat162float(*(const __hip_bfloat16*)&u.w);
        acc.x += v.x * at.x; acc.y += v.y * at.y;
        acc.z += v.z * at.z; acc.w += v.w * at.w;
    }

    float4 b = *(const float4*)(&bias[lane * 4]);
    acc.x += b.x; acc.y += b.y; acc.z += b.z; acc.w += b.w;

    // reduce over lanes differing in bits 3..5: sums the 8 head-copies of f2
    for (int m = 8; m <= 32; m <<= 1) {
        acc.x += __shfl_xor(acc.x, m, 64);
        acc.y += __shfl_xor(acc.y, m, 64);
        acc.z += __shfl_xor(acc.z, m, 64);
        acc.w += __shfl_xor(acc.w, m, 64);
    }
    if (lane < 8) {
        float4 o;
        o.x = acc.x * 0.125f; o.y = acc.y * 0.125f;
        o.z = acc.z * 0.125f; o.w = acc.w * 0.125f;
        o.x = (o.x > 0.f) ? o.x : (expf(o.x) - 1.f);
        o.y = (o.y > 0.f) ? o.y : (expf(o.y) - 1.f);
        o.z = (o.z > 0.f) ? o.z : (expf(o.z) - 1.f);
        o.w = (o.w > 0.f) ? o.w : (expf(o.w) - 1.f);
        *(float4*)(&ret[n * FOUT + lane * 4]) = o;
    }
}

extern "C" void kernel_launch(void* const* d_in, const int* in_sizes, int n_in,
                              void* d_out, int out_size, void* d_ws, size_t ws_size,
                              hipStream_t stream)
{
    const float* x      = (const float*)d_in[0];
    const float* fc_w   = (const float*)d_in[1];
    const float* attn_l = (const float*)d_in[2];
    const float* attn_r = (const float*)d_in[3];
    const float* bias   = (const float*)d_in[4];
    const int*   src    = (const int*)d_in[5];
    const int*   dst    = (const int*)d_in[6];
    const int*   etype  = (const int*)d_in[7];

    float* out_attn = (float*)d_out;                 // [E, 1, HEADS]
    float* out_ret  = out_attn + (size_t)EE * HEADS; // [N, FOUT]

    // workspace layout (bytes)
    char* ws = (char*)d_ws;
    __hip_bfloat16* nfh = (__hip_bfloat16*)(ws);     // 25.6 MB
    float* a1     = (float*)(ws + 25600000);         // 1.6 MB
    float* nt     = (float*)(ws + 27200000);         // 25.6 MB
    float* den    = (float*)(ws + 52800000);         // 1.6 MB
    int*   deg    = (int*)(ws + 54400000);           // 200 KB
    int*   cursor = (int*)(ws + 54600000);           // 200 KB
    int*   rowptr = (int*)(ws + 54800000);           // 200 KB
    int*   eidx   = (int*)(ws + 55000192);           // 3.2 MB

    // zero per-launch state: den, deg, cursor (den..cursor contiguous region)
    hipMemsetAsync(den, 0, (size_t)(NN * HEADS * 4 + 400000), stream);

    k_project<<<(NN + NPB - 1) / NPB, 256, 0, stream>>>(x, fc_w, attn_l, attn_r,
                                                        nfh, a1, nt);

    k_hist<<<(EE + 255) / 256, 256, 0, stream>>>(dst, deg);
    k_scan<<<1, SCAN_T, 0, stream>>>(deg, rowptr);
    k_scatter<<<(EE + 255) / 256, 256, 0, stream>>>(dst, rowptr, cursor, eidx);

    int eblk = (EE * HEADS + 255) / 256;
    k_edge<<<eblk, 256, 0, stream>>>(a1, nt, src, dst, etype, out_attn, den);

    k_aggfused<<<(NN + 3) / 4, 256, 0, stream>>>(nfh, src, rowptr, deg, eidx, den,
                                                 bias, out_attn, out_ret);
}

// Round 5
// 337.815 us; speedup vs baseline: 1.8485x; 1.4074x over previous
//
#include <hip/hip_runtime.h>
#include <hip/hip_bf16.h>
#include <math.h>

#define NN 50000
#define EE 800000
#define FIN 128
#define FOUT 32
#define HEADS 8
#define NT 16
#define HF 256          // HEADS*FOUT
#define TH (NT*HEADS)   // 128
#define CMAX 128        // max per-node degree held in LDS (Poisson(16) max ~45)

// ---- Kernel A: projection + a1 + node_type; nf stored as bf16 ----
#define NPB 16
__global__ __launch_bounds__(256) void k_project(
    const float* __restrict__ x, const float* __restrict__ fc_w,
    const float* __restrict__ attn_l, const float* __restrict__ attn_r,
    __hip_bfloat16* __restrict__ nfh, float* __restrict__ a1,
    float* __restrict__ nt)
{
    __shared__ float xs[NPB][FIN];   // 8 KB
    __shared__ float ps[NPB][HF];    // 16 KB
    const int t = threadIdx.x;
    const int node0 = blockIdx.x * NPB;

    for (int i = t; i < NPB * FIN; i += 256) {
        int ni = i >> 7, k = i & 127;
        int n = node0 + ni;
        xs[ni][k] = (n < NN) ? x[n * FIN + k] : 0.f;
    }
    __syncthreads();

    float acc[NPB];
#pragma unroll
    for (int i = 0; i < NPB; i++) acc[i] = 0.f;
#pragma unroll 4
    for (int k = 0; k < FIN; k++) {
        float w = fc_w[k * HF + t];
#pragma unroll
        for (int i = 0; i < NPB; i++) acc[i] += xs[i][k] * w;
    }
#pragma unroll
    for (int i = 0; i < NPB; i++) {
        ps[i][t] = acc[i];
        int n = node0 + i;
        if (n < NN) nfh[(size_t)n * HF + t] = __float2bfloat16(acc[i]);
    }
    __syncthreads();

    if (t < NPB * HEADS) {
        int ni = t >> 3, h = t & 7;
        float s = 0.f;
#pragma unroll
        for (int f = 0; f < FOUT; f++) s += ps[ni][f * HEADS + h] * attn_l[f * HEADS + h];
        int n = node0 + ni;
        if (n < NN) a1[n * HEADS + h] = s;
    }
    for (int task = t; task < NPB * TH; task += 256) {
        int ni = task / TH;
        int rem = task % TH;
        int tt = rem >> 3, h = rem & 7;
        const float* ar = attn_r + tt * (FOUT * HEADS);
        float s = 0.f;
#pragma unroll
        for (int f = 0; f < FOUT; f++) s += ps[ni][f * HEADS + h] * ar[f * HEADS + h];
        int n = node0 + ni;
        if (n < NN) nt[n * TH + rem] = s;
    }
}

// ---- CSR build: histogram of dst ----
__global__ __launch_bounds__(256) void k_hist(
    const int* __restrict__ dst, int* __restrict__ deg)
{
    int e = blockIdx.x * 256 + threadIdx.x;
    if (e >= EE) return;
    atomicAdd(&deg[dst[e]], 1);
}

// ---- CSR build: single-block exclusive scan deg -> rowptr[NN+1] ----
#define SCAN_T 1024
__global__ __launch_bounds__(1024) void k_scan(
    const int* __restrict__ deg, int* __restrict__ rowptr)
{
    __shared__ int part[SCAN_T];
    const int t = threadIdx.x;
    const int CH = (NN + SCAN_T - 1) / SCAN_T;  // 49
    int begin = t * CH;
    int end = begin + CH; if (end > NN) end = NN;
    if (begin > NN) begin = NN;
    int s = 0;
    for (int i = begin; i < end; i++) s += deg[i];
    part[t] = s;
    __syncthreads();
    for (int off = 1; off < SCAN_T; off <<= 1) {
        int v = (t >= off) ? part[t - off] : 0;
        __syncthreads();
        part[t] += v;
        __syncthreads();
    }
    int excl = (t == 0) ? 0 : part[t - 1];
    for (int i = begin; i < end; i++) {
        rowptr[i] = excl;
        excl += deg[i];
    }
    if (t == SCAN_T - 1) rowptr[NN] = EE;
}

// ---- CSR build: scatter records {e, src*TH+etype*HEADS}; deg doubles as cursor ----
__global__ __launch_bounds__(256) void k_scatter(
    const int* __restrict__ dst, const int* __restrict__ src,
    const int* __restrict__ et, const int* __restrict__ rowptr,
    int* __restrict__ deg, int2* __restrict__ recs)
{
    int e = blockIdx.x * 256 + threadIdx.x;
    if (e >= EE) return;
    int d = dst[e];
    int pos = atomicAdd(&deg[d], -1) - 1;      // unique slot deg-1..0
    int2 rec;
    rec.x = e;
    rec.y = src[e] * TH + et[e] * HEADS;
    recs[rowptr[d] + pos] = rec;
}

// ---- Fused per-node kernel: logits+exp (edge×head lanes, no redundancy),
//      softmax denom in registers, gather-aggregate, attn write, epilogue ----
// One 64-lane wave per dst node.
__global__ __launch_bounds__(256) void k_agg(
    const __hip_bfloat16* __restrict__ nfh, const float* __restrict__ a1,
    const float* __restrict__ nt, const int2* __restrict__ recs,
    const int* __restrict__ rowptr, const float* __restrict__ bias,
    float* __restrict__ A, float* __restrict__ ret)
{
    __shared__ float exs[4][CMAX * HEADS];  // 16 KB
    __shared__ int   sbuf[4][CMAX];         // 2 KB
    __shared__ int   ebuf[4][CMAX];         // 2 KB
    const int w    = threadIdx.x >> 6;
    const int lane = threadIdx.x & 63;
    const int n = blockIdx.x * 4 + w;
    if (n >= NN) return;
    const int start = rowptr[n];
    const int cnt   = rowptr[n + 1] - start;
    const int h  = lane & 7;    // head for logit phase
    const int ei = lane >> 3;   // edge-in-group for logit phase
    const int half = lane & 1;  // heads of aggregate columns lane*4+c are half*4+c

    const float a1h = a1[n * HEADS + h];
    float denl = 0.f;
    float4 acc = make_float4(0.f, 0.f, 0.f, 0.f);

    for (int base = 0; base < cnt; base += CMAX) {
        const int c = (cnt - base < CMAX) ? (cnt - base) : CMAX;
        // Phase A: logits + exp, 8 edges x 8 heads per step, each computed once
        for (int p0 = 0; p0 < c; p0 += 8) {
            int p = p0 + ei;
            if (p < c) {
                int2 rec = recs[start + base + p];
                float a = a1h + nt[rec.y + h];
                a = (a > 0.f) ? a : 0.2f * a;
                float ex = expf(a);
                exs[w][p * HEADS + h] = ex;
                denl += ex;
                if (h == 0) { sbuf[w][p] = rec.y >> 7; ebuf[w][p] = rec.x; }
            }
        }
        asm volatile("s_waitcnt lgkmcnt(0)" ::: "memory");
        // Phase B: unnormalized aggregate, all 64 lanes per edge
        for (int p = 0; p < c; p++) {
            int s = sbuf[w][p];
            float4 ex4 = *(const float4*)(&exs[w][p * HEADS + half * 4]);
            uint2 u = *(const uint2*)((const unsigned short*)nfh + (size_t)s * HF + lane * 4);
            float vx = __uint_as_float(u.x << 16);
            float vy = __uint_as_float(u.x & 0xFFFF0000u);
            float vz = __uint_as_float(u.y << 16);
            float vw = __uint_as_float(u.y & 0xFFFF0000u);
            acc.x += vx * ex4.x; acc.y += vy * ex4.y;
            acc.z += vz * ex4.z; acc.w += vw * ex4.w;
        }
        asm volatile("s_waitcnt lgkmcnt(0)" ::: "memory");
    }

    // denom: sum over the 8 edge-lanes holding the same head
    float den = denl;
    den += __shfl_xor(den, 8, 64);
    den += __shfl_xor(den, 16, 64);
    den += __shfl_xor(den, 32, 64);
    const float inv = (den > 0.f) ? 1.f / den : 0.f;

    // attn writes (normalized), once per edge-head
    if (cnt <= CMAX) {
        for (int p0 = 0; p0 < cnt; p0 += 8) {
            int p = p0 + ei;
            if (p < cnt) A[ebuf[w][p] * HEADS + h] = exs[w][p * HEADS + h] * inv;
        }
    } else {  // fallback (degree > CMAX): recompute logits
        for (int p0 = 0; p0 < cnt; p0 += 8) {
            int p = p0 + ei;
            if (p < cnt) {
                int2 rec = recs[start + p];
                float a = a1h + nt[rec.y + h];
                a = (a > 0.f) ? a : 0.2f * a;
                A[rec.x * HEADS + h] = expf(a) * inv;
            }
        }
    }

    // normalize acc (per-column head inv via shfl), + bias, head-mean, ELU
    float4 invc;
    invc.x = __shfl(inv, half * 4 + 0, 64);
    invc.y = __shfl(inv, half * 4 + 1, 64);
    invc.z = __shfl(inv, half * 4 + 2, 64);
    invc.w = __shfl(inv, half * 4 + 3, 64);
    float4 b = *(const float4*)(&bias[lane * 4]);
    acc.x = acc.x * invc.x + b.x;
    acc.y = acc.y * invc.y + b.y;
    acc.z = acc.z * invc.z + b.z;
    acc.w = acc.w * invc.w + b.w;

    for (int m = 8; m <= 32; m <<= 1) {
        acc.x += __shfl_xor(acc.x, m, 64);
        acc.y += __shfl_xor(acc.y, m, 64);
        acc.z += __shfl_xor(acc.z, m, 64);
        acc.w += __shfl_xor(acc.w, m, 64);
    }
    if (lane < 8) {
        float4 o;
        o.x = acc.x * 0.125f; o.y = acc.y * 0.125f;
        o.z = acc.z * 0.125f; o.w = acc.w * 0.125f;
        o.x = (o.x > 0.f) ? o.x : (expf(o.x) - 1.f);
        o.y = (o.y > 0.f) ? o.y : (expf(o.y) - 1.f);
        o.z = (o.z > 0.f) ? o.z : (expf(o.z) - 1.f);
        o.w = (o.w > 0.f) ? o.w : (expf(o.w) - 1.f);
        *(float4*)(&ret[n * FOUT + lane * 4]) = o;
    }
}

extern "C" void kernel_launch(void* const* d_in, const int* in_sizes, int n_in,
                              void* d_out, int out_size, void* d_ws, size_t ws_size,
                              hipStream_t stream)
{
    const float* x      = (const float*)d_in[0];
    const float* fc_w   = (const float*)d_in[1];
    const float* attn_l = (const float*)d_in[2];
    const float* attn_r = (const float*)d_in[3];
    const float* bias   = (const float*)d_in[4];
    const int*   src    = (const int*)d_in[5];
    const int*   dst    = (const int*)d_in[6];
    const int*   etype  = (const int*)d_in[7];

    float* out_attn = (float*)d_out;                 // [E, 1, HEADS]
    float* out_ret  = out_attn + (size_t)EE * HEADS; // [N, FOUT]

    // workspace layout (bytes)
    char* ws = (char*)d_ws;
    __hip_bfloat16* nfh = (__hip_bfloat16*)(ws);     // 25.6 MB
    float* a1     = (float*)(ws + 25600000);         // 1.6 MB
    float* nt     = (float*)(ws + 27200000);         // 25.6 MB
    int*   deg    = (int*)(ws + 52800000);           // 200 KB (also scatter cursor)
    int*   rowptr = (int*)(ws + 53000000);           // 200 KB + 4
    int2*  recs   = (int2*)(ws + 53200008);          // 6.4 MB

    hipMemsetAsync(deg, 0, (size_t)NN * 4, stream);

    k_project<<<(NN + NPB - 1) / NPB, 256, 0, stream>>>(x, fc_w, attn_l, attn_r,
                                                        nfh, a1, nt);

    k_hist<<<(EE + 255) / 256, 256, 0, stream>>>(dst, deg);
    k_scan<<<1, SCAN_T, 0, stream>>>(deg, rowptr);
    k_scatter<<<(EE + 255) / 256, 256, 0, stream>>>(dst, src, etype, rowptr, deg, recs);

    k_agg<<<(NN + 3) / 4, 256, 0, stream>>>(nfh, a1, nt, recs, rowptr, bias,
                                            out_attn, out_ret);
}